// Round 6
// baseline (938.225 us; speedup 1.0000x reference)
//
#include <hip/hip_runtime.h>
#include <hip/hip_bf16.h>
#include <stdint.h>

#define IN_CH 64
#define OUT_CH 128
#define CT_ENT 64    // entries per contrib block
#define FT_S 65      // padded LDS stride (floats) for transposed f tile
#define GS_RPB 64    // rows per block (gather)

// ---------- fast path ----------

// Zero counts[n_out] and sums[256].
__global__ void __launch_bounds__(256) zero_meta_kernel(
    int* __restrict__ counts, int n_out, float* __restrict__ sums) {
    int i = blockIdx.x * 256 + threadIdx.x;
    if (i < n_out) counts[i] = 0;
    if (blockIdx.x == 0) sums[threadIdx.x] = 0.f;
}

// Wt[k][c][i] = W[k][i][c]  (295 KB, runs in ~us)
__global__ void __launch_bounds__(256) wt_transpose_kernel(
    const float* __restrict__ W, float* __restrict__ Wt) {
    int idx = blockIdx.x * 256 + threadIdx.x;
    if (idx >= 9 * OUT_CH * IN_CH) return;
    int i = idx & (IN_CH - 1);
    int c = (idx >> 6) & (OUT_CH - 1);
    int k = idx >> 13;
    Wt[idx] = W[((size_t)k * IN_CH + i) * OUT_CH + c];
}

// Phase 1: per-k GEMM tiles. Block = 64 entries x 128 channels, 4 waves.
// lane = entry. f tile staged via coalesced vector loads -> LDS (transposed,
// pad 65) -> VGPRs. W rows (Wt, contiguous per channel) are wave-uniform ->
// scalar loads from K$. No mask: invalid entries compute garbage that the
// gather phase never reads (in_idx of padded entries is 0 -> safe address).
__global__ void __launch_bounds__(256) contrib_kernel(
    const float* __restrict__ feats,
    const float* __restrict__ Wt,     // [9][128][64]
    const int* __restrict__ in_idx,
    float* __restrict__ contrib,      // [9R, 128]
    int R)
{
    __shared__ float fT[IN_CH * FT_S];   // fT[i*FT_S + e] = f[e][i]
    const int k = blockIdx.y;
    const int r0 = blockIdx.x * CT_ENT;
    const int t = threadIdx.x;
    const int* __restrict__ inK = in_idx + (size_t)k * R;

    // Stage: thread covers row = t>>2, float4 index q = (t&3) + 4*it.
    {
        int row = t >> 2;
        int rr = r0 + row; if (rr >= R) rr = R - 1;
        int fi = inK[rr];
        const float4* __restrict__ frow = (const float4*)(feats + (size_t)fi * IN_CH);
#pragma unroll
        for (int it = 0; it < 4; ++it) {
            int q = (t & 3) + 4 * it;
            float4 v = frow[q];
            int ib = q * 4;
            fT[(ib + 0) * FT_S + row] = v.x;
            fT[(ib + 1) * FT_S + row] = v.y;
            fT[(ib + 2) * FT_S + row] = v.z;
            fT[(ib + 3) * FT_S + row] = v.w;
        }
    }
    __syncthreads();

    const int lane = t & 63;                    // entry within tile
    const int w = t >> 6;                       // wave id
    const int cbase = w * 32;                   // this wave's 32 channels
    const float* __restrict__ wtK = Wt + ((size_t)k * OUT_CH + cbase) * IN_CH;

    float acc[32];
#pragma unroll
    for (int c = 0; c < 32; ++c) acc[c] = 0.f;

    float fv[16];
#pragma unroll
    for (int j = 0; j < 16; ++j) fv[j] = fT[j * FT_S + lane];

#pragma unroll
    for (int ch = 0; ch < 4; ++ch) {
        float fn[16];
        if (ch < 3) {
#pragma unroll
            for (int j = 0; j < 16; ++j) fn[j] = fT[(ch * 16 + 16 + j) * FT_S + lane];
        }
#pragma unroll
        for (int c = 0; c < 32; ++c) {
            const float* __restrict__ wr = wtK + c * IN_CH + ch * 16;
            float s0 = 0.f, s1 = 0.f;
#pragma unroll
            for (int j = 0; j < 16; j += 2) {
                s0 = fmaf(fv[j],     wr[j],     s0);
                s1 = fmaf(fv[j + 1], wr[j + 1], s1);
            }
            acc[c] += s0 + s1;
        }
        if (ch < 3) {
#pragma unroll
            for (int j = 0; j < 16; ++j) fv[j] = fn[j];
        }
    }

    if (r0 + lane < R) {
        float4* __restrict__ orow =
            (float4*)(contrib + ((size_t)k * R + r0 + lane) * OUT_CH + cbase);
#pragma unroll
        for (int cq = 0; cq < 8; ++cq) {
            orow[cq] = make_float4(acc[cq * 4], acc[cq * 4 + 1],
                                   acc[cq * 4 + 2], acc[cq * 4 + 3]);
        }
    }
}

// Inverse rulebook: append entry id to its out row's fixed-width list.
__global__ void __launch_bounds__(256) build_kernel(
    const int* __restrict__ out_idx,
    const int* __restrict__ mask,
    int* __restrict__ counts,
    int* __restrict__ list,   // [n_out, 9]
    int nE)
{
    int e = blockIdx.x * 256 + threadIdx.x;
    if (e >= nE || !mask[e]) return;
    int out = out_idx[e];
    int slot = atomicAdd(&counts[out], 1);
    list[(size_t)out * 9 + slot] = e;
}

// Phase 2: one wave per row (uniform row -> scalar meta loads); 9 slots
// loaded unconditionally; contrib float2 loads independent. Fused BN stats.
__global__ void __launch_bounds__(256) gather_stats_kernel(
    const float2* __restrict__ contrib2,   // [9R, 64]
    const int* __restrict__ counts,
    const int* __restrict__ list,
    float2* __restrict__ acc2,             // [n_out, 64]
    float* __restrict__ sums,              // [256]
    int n_out)
{
    const int lane = threadIdx.x & 63;
    const int w = __builtin_amdgcn_readfirstlane(threadIdx.x >> 6);
    const int rbase = blockIdx.x * GS_RPB;

    float sx = 0.f, sy = 0.f, qx = 0.f, qy = 0.f;

#pragma unroll 2
    for (int it = 0; it < GS_RPB / 4; ++it) {
        int r = rbase + it * 4 + w;
        if (r < n_out) {
            int cnt = __builtin_amdgcn_readfirstlane(counts[r]);
            const int* __restrict__ lp = list + (size_t)r * 9;
            int e[9];
#pragma unroll
            for (int j = 0; j < 9; ++j)
                e[j] = __builtin_amdgcn_readfirstlane(lp[j]);
            float vx = 0.f, vy = 0.f;
#pragma unroll
            for (int j = 0; j < 9; ++j) {
                if (j < cnt) {
                    float2 t = contrib2[(size_t)e[j] * 64 + lane];
                    vx += t.x; vy += t.y;
                }
            }
            acc2[(size_t)r * 64 + lane] = make_float2(vx, vy);
            sx += vx; sy += vy; qx += vx * vx; qy += vy * vy;
        }
    }

    __shared__ float redS[4][128];
    __shared__ float redQ[4][128];
    redS[w][lane * 2] = sx;  redS[w][lane * 2 + 1] = sy;
    redQ[w][lane * 2] = qx;  redQ[w][lane * 2 + 1] = qy;
    __syncthreads();
    if (threadIdx.x < 128) {
        int cch = threadIdx.x;
        float a = redS[0][cch] + redS[1][cch] + redS[2][cch] + redS[3][cch];
        float b = redQ[0][cch] + redQ[1][cch] + redQ[2][cch] + redQ[3][cch];
        atomicAdd(&sums[cch], a);
        atomicAdd(&sums[OUT_CH + cch], b);
    }
}

// y = gamma*(x-mean)*rsqrt(var+eps)+beta, relu; in-place, float4.
__global__ void __launch_bounds__(256) bn_relu_kernel(
    float4* __restrict__ out,
    const float* __restrict__ sums,
    const float* __restrict__ gamma,
    const float* __restrict__ beta,
    int total4, float inv_n)
{
    int idx = blockIdx.x * 256 + threadIdx.x;
    if (idx >= total4) return;
    int c0 = (idx & 31) * 4;
    float4 v = out[idx];
    float r[4] = {v.x, v.y, v.z, v.w};
#pragma unroll
    for (int j = 0; j < 4; ++j) {
        int c = c0 + j;
        float mean = sums[c] * inv_n;
        float var = sums[OUT_CH + c] * inv_n - mean * mean;
        float scale = gamma[c] * rsqrtf(var + 1e-5f);
        float y = (r[j] - mean) * scale + beta[c];
        r[j] = fmaxf(y, 0.0f);
    }
    out[idx] = make_float4(r[0], r[1], r[2], r[3]);
}

// ---------- fallback (atomic scatter) if ws too small ----------

__global__ void __launch_bounds__(256) zero_kernel(float4* __restrict__ out, int n4,
                                                   float* __restrict__ sums) {
    int idx = blockIdx.x * 256 + threadIdx.x;
    if (idx < n4) out[idx] = make_float4(0.f, 0.f, 0.f, 0.f);
    if (blockIdx.x == 0 && threadIdx.x < 2 * OUT_CH) sums[threadIdx.x] = 0.f;
}

__global__ void __launch_bounds__(256) scatter_gemm_kernel(
    const float* __restrict__ feats,
    const float* __restrict__ W,
    const int* __restrict__ in_idx,
    const int* __restrict__ out_idx,
    const int* __restrict__ mask,
    float* __restrict__ acc,
    int R)
{
    const int lane = threadIdx.x & 63;
    const int waveId = threadIdx.x >> 6;
    const int half = waveId & 1;
    const int pair = waveId >> 1;
    const int k = blockIdx.y;
    const int c = half * 64 + lane;

    float wreg[IN_CH];
    const float* __restrict__ wp = W + (size_t)k * IN_CH * OUT_CH + c;
#pragma unroll
    for (int i = 0; i < IN_CH; ++i) wreg[i] = wp[i * OUT_CH];

    const int r0 = blockIdx.x * 128;
    const int rEnd = min(r0 + 128, R);
    const int* __restrict__ maskK = mask + (size_t)k * R;
    const int* __restrict__ inK = in_idx + (size_t)k * R;
    const int* __restrict__ outK = out_idx + (size_t)k * R;

    for (int r = r0 + pair; r < rEnd; r += 2) {
        if (!__builtin_amdgcn_readfirstlane(maskK[r])) continue;
        int in = __builtin_amdgcn_readfirstlane(inK[r]);
        int out = __builtin_amdgcn_readfirstlane(outK[r]);
        const float* __restrict__ f = feats + (size_t)in * IN_CH;
        float s = 0.f, s1 = 0.f;
#pragma unroll
        for (int i = 0; i < IN_CH; i += 2) {
            s = fmaf(wreg[i], f[i], s);
            s1 = fmaf(wreg[i + 1], f[i + 1], s1);
        }
        atomicAdd(acc + (size_t)out * OUT_CH + c, s + s1);
    }
}

__global__ void __launch_bounds__(128) stats_kernel(
    const float* __restrict__ acc,
    float* __restrict__ sums,
    int n_out)
{
    int c = threadIdx.x;
    float s = 0.0f, s2 = 0.0f;
    for (int r = blockIdx.x; r < n_out; r += gridDim.x) {
        float v = acc[(size_t)r * OUT_CH + c];
        s += v;
        s2 += v * v;
    }
    atomicAdd(&sums[c], s);
    atomicAdd(&sums[OUT_CH + c], s2);
}

// ---------- launch ----------

extern "C" void kernel_launch(void* const* d_in, const int* in_sizes, int n_in,
                              void* d_out, int out_size, void* d_ws, size_t ws_size,
                              hipStream_t stream) {
    const float* feats   = (const float*)d_in[0];
    const float* W       = (const float*)d_in[1];
    const float* gamma   = (const float*)d_in[2];
    const float* beta    = (const float*)d_in[3];
    const int*   in_idx  = (const int*)d_in[4];
    const int*   out_idx = (const int*)d_in[5];
    const int*   mask    = (const int*)d_in[6];   // bool stored as int32

    const int R = in_sizes[4] / 9;
    const int nE = 9 * R;
    const int n_out = out_size / OUT_CH;
    float* acc = (float*)d_out;

    size_t off_contrib = 0;
    size_t sz_contrib = (size_t)nE * OUT_CH * sizeof(float);
    size_t off_counts = off_contrib + sz_contrib;
    size_t off_list = (off_counts + (size_t)n_out * 4 + 15) & ~(size_t)15;
    size_t off_sums = (off_list + (size_t)n_out * 9 * 4 + 15) & ~(size_t)15;
    size_t off_wt   = (off_sums + 1024 + 15) & ~(size_t)15;
    size_t needed = off_wt + (size_t)9 * OUT_CH * IN_CH * sizeof(float);

    if (ws_size >= needed) {
        float* contrib = (float*)((char*)d_ws + off_contrib);
        int*   counts  = (int*)((char*)d_ws + off_counts);
        int*   list    = (int*)((char*)d_ws + off_list);
        float* sums    = (float*)((char*)d_ws + off_sums);
        float* Wt      = (float*)((char*)d_ws + off_wt);

        zero_meta_kernel<<<(n_out + 255) / 256, 256, 0, stream>>>(counts, n_out, sums);

        wt_transpose_kernel<<<(9 * OUT_CH * IN_CH + 255) / 256, 256, 0, stream>>>(W, Wt);

        dim3 grid1((R + CT_ENT - 1) / CT_ENT, 9);
        contrib_kernel<<<grid1, 256, 0, stream>>>(feats, Wt, in_idx, contrib, R);

        build_kernel<<<(nE + 255) / 256, 256, 0, stream>>>(out_idx, mask, counts, list, nE);

        int blocks2 = (n_out + GS_RPB - 1) / GS_RPB;
        gather_stats_kernel<<<blocks2, 256, 0, stream>>>(
            (const float2*)contrib, counts, list, (float2*)acc, sums, n_out);

        int total4 = out_size / 4;
        bn_relu_kernel<<<(total4 + 255) / 256, 256, 0, stream>>>(
            (float4*)acc, sums, gamma, beta, total4, 1.0f / (float)n_out);
    } else {
        float* sums = (float*)d_ws;
        int n4 = out_size / 4;
        zero_kernel<<<(n4 + 255) / 256, 256, 0, stream>>>((float4*)acc, n4, sums);

        dim3 grid((R + 127) / 128, 9);
        scatter_gemm_kernel<<<grid, 256, 0, stream>>>(feats, W, in_idx, out_idx, mask, acc, R);

        stats_kernel<<<2048, 128, 0, stream>>>(acc, sums, n_out);

        int total4 = out_size / 4;
        bn_relu_kernel<<<(total4 + 255) / 256, 256, 0, stream>>>(
            (float4*)acc, sums, gamma, beta, total4, 1.0f / (float)n_out);
    }
}

// Round 7
// 555.042 us; speedup vs baseline: 1.6904x; 1.6904x over previous
//
#include <hip/hip_runtime.h>
#include <hip/hip_bf16.h>
#include <stdint.h>

#define IN_CH 64
#define OUT_CH 128
#define GS_RPB 64    // rows per block (gather)

typedef __bf16 bf16x8 __attribute__((ext_vector_type(8)));
typedef float  f32x4  __attribute__((ext_vector_type(4)));

__device__ inline unsigned short f2bf(float f) {
    unsigned u = __float_as_uint(f);
    unsigned r = (u + 0x7fffu + ((u >> 16) & 1u)) >> 16;
    return (unsigned short)r;
}

// ---------- fast path ----------

// Zero counts[n_out] and sums[256].
__global__ void __launch_bounds__(256) zero_meta_kernel(
    int* __restrict__ counts, int n_out, float* __restrict__ sums) {
    int i = blockIdx.x * 256 + threadIdx.x;
    if (i < n_out) counts[i] = 0;
    if (blockIdx.x == 0) sums[threadIdx.x] = 0.f;
}

// feats fp32 -> bf16 (RNE). n4 = N_in*IN_CH/4.
__global__ void __launch_bounds__(256) feats_bf16_kernel(
    const float4* __restrict__ f4, ushort* __restrict__ fb, int n4) {
    int i = blockIdx.x * 256 + threadIdx.x;
    if (i >= n4) return;
    float4 v = f4[i];
    ushort4 o;
    o.x = f2bf(v.x); o.y = f2bf(v.y); o.z = f2bf(v.z); o.w = f2bf(v.w);
    ((ushort4*)fb)[i] = o;
}

// Wbt[k][c][i] = bf16(W[k][i][c]); [9][128][64]
__global__ void __launch_bounds__(256) wbt_kernel(
    const float* __restrict__ W, ushort* __restrict__ wbt) {
    int idx = blockIdx.x * 256 + threadIdx.x;
    if (idx >= 9 * OUT_CH * IN_CH) return;
    int i = idx & (IN_CH - 1);
    int c = (idx >> 6) & (OUT_CH - 1);
    int k = idx >> 13;
    wbt[idx] = f2bf(W[((size_t)k * IN_CH + i) * OUT_CH + c]);
}

// Phase 1 via MFMA. Block = 4 waves; wave = 16 entries x 128 channels for
// kernel-offset k = blockIdx.y. A-frag gathered straight from bf16 feats
// (lane: row = e0+(lane&15), i-chunk = quad*8); B-frags (k-invariant) from
// L2-resident Wbt. D layout: row=quad*4+reg (entry), col=lane&15 (channel).
// No mask: padded entries compute garbage the gather never reads.
__global__ void __launch_bounds__(256) contrib_mfma_kernel(
    const ushort* __restrict__ fb,    // [N_in][64] bf16
    const ushort* __restrict__ wbt,   // [9][128][64] bf16
    const int* __restrict__ in_idx,
    float* __restrict__ contrib,      // [9R][128] fp32
    int R)
{
    const int k = blockIdx.y;
    const int lane = threadIdx.x & 63;
    const int wv = threadIdx.x >> 6;
    const int e0 = blockIdx.x * 64 + wv * 16;
    if (e0 >= R) return;
    const int col = lane & 15;
    const int quad = lane >> 4;

    // B-frags: wbt[k][g*16+col][quad*8 + j] (+32 for second K-step)
    bf16x8 B0[8], B1[8];
    const ushort* __restrict__ wk = wbt + (size_t)k * OUT_CH * IN_CH;
#pragma unroll
    for (int g = 0; g < 8; ++g) {
        const ushort* p = wk + (size_t)(g * 16 + col) * IN_CH + quad * 8;
        B0[g] = *(const bf16x8*)p;
        B1[g] = *(const bf16x8*)(p + 32);
    }

    // A-frag: gathered feature row chunk
    int ee = e0 + col; if (ee >= R) ee = R - 1;
    int iv = in_idx[(size_t)k * R + ee];
    const ushort* __restrict__ frow = fb + (size_t)iv * IN_CH + quad * 8;
    bf16x8 A0 = *(const bf16x8*)frow;
    bf16x8 A1 = *(const bf16x8*)(frow + 32);

    f32x4 acc[8];
#pragma unroll
    for (int g = 0; g < 8; ++g) acc[g] = (f32x4){0.f, 0.f, 0.f, 0.f};
#pragma unroll
    for (int g = 0; g < 8; ++g) {
        acc[g] = __builtin_amdgcn_mfma_f32_16x16x32_bf16(A0, B0[g], acc[g], 0, 0, 0);
        acc[g] = __builtin_amdgcn_mfma_f32_16x16x32_bf16(A1, B1[g], acc[g], 0, 0, 0);
    }

    // Store D: entry row = e0 + quad*4 + r, channel = g*16 + col.
    float* __restrict__ cb = contrib + (size_t)k * R * OUT_CH;
#pragma unroll
    for (int r = 0; r < 4; ++r) {
        int row = e0 + quad * 4 + r;
        if (row < R) {
            float* __restrict__ rp = cb + (size_t)row * OUT_CH + col;
#pragma unroll
            for (int g = 0; g < 8; ++g) rp[g * 16] = acc[g][r];
        }
    }
}

// Inverse rulebook: append entry id to its out row's fixed-width list.
__global__ void __launch_bounds__(256) build_kernel(
    const int* __restrict__ out_idx,
    const int* __restrict__ mask,
    int* __restrict__ counts,
    int* __restrict__ list,   // [n_out, 9]
    int nE)
{
    int e = blockIdx.x * 256 + threadIdx.x;
    if (e >= nE || !mask[e]) return;
    int out = out_idx[e];
    int slot = atomicAdd(&counts[out], 1);
    list[(size_t)out * 9 + slot] = e;
}

// Phase 2: one wave per row (uniform row -> scalar meta loads); 9 slots
// loaded unconditionally; contrib float2 loads independent. Fused BN stats.
__global__ void __launch_bounds__(256) gather_stats_kernel(
    const float2* __restrict__ contrib2,   // [9R, 64]
    const int* __restrict__ counts,
    const int* __restrict__ list,
    float2* __restrict__ acc2,             // [n_out, 64]
    float* __restrict__ sums,              // [256]
    int n_out)
{
    const int lane = threadIdx.x & 63;
    const int w = __builtin_amdgcn_readfirstlane(threadIdx.x >> 6);
    const int rbase = blockIdx.x * GS_RPB;

    float sx = 0.f, sy = 0.f, qx = 0.f, qy = 0.f;

#pragma unroll 2
    for (int it = 0; it < GS_RPB / 4; ++it) {
        int r = rbase + it * 4 + w;
        if (r < n_out) {
            int cnt = __builtin_amdgcn_readfirstlane(counts[r]);
            const int* __restrict__ lp = list + (size_t)r * 9;
            int e[9];
#pragma unroll
            for (int j = 0; j < 9; ++j)
                e[j] = __builtin_amdgcn_readfirstlane(lp[j]);
            float vx = 0.f, vy = 0.f;
#pragma unroll
            for (int j = 0; j < 9; ++j) {
                if (j < cnt) {
                    float2 t = contrib2[(size_t)e[j] * 64 + lane];
                    vx += t.x; vy += t.y;
                }
            }
            acc2[(size_t)r * 64 + lane] = make_float2(vx, vy);
            sx += vx; sy += vy; qx += vx * vx; qy += vy * vy;
        }
    }

    __shared__ float redS[4][128];
    __shared__ float redQ[4][128];
    redS[w][lane * 2] = sx;  redS[w][lane * 2 + 1] = sy;
    redQ[w][lane * 2] = qx;  redQ[w][lane * 2 + 1] = qy;
    __syncthreads();
    if (threadIdx.x < 128) {
        int cch = threadIdx.x;
        float a = redS[0][cch] + redS[1][cch] + redS[2][cch] + redS[3][cch];
        float b = redQ[0][cch] + redQ[1][cch] + redQ[2][cch] + redQ[3][cch];
        atomicAdd(&sums[cch], a);
        atomicAdd(&sums[OUT_CH + cch], b);
    }
}

// y = gamma*(x-mean)*rsqrt(var+eps)+beta, relu; in-place, float4.
__global__ void __launch_bounds__(256) bn_relu_kernel(
    float4* __restrict__ out,
    const float* __restrict__ sums,
    const float* __restrict__ gamma,
    const float* __restrict__ beta,
    int total4, float inv_n)
{
    int idx = blockIdx.x * 256 + threadIdx.x;
    if (idx >= total4) return;
    int c0 = (idx & 31) * 4;
    float4 v = out[idx];
    float r[4] = {v.x, v.y, v.z, v.w};
#pragma unroll
    for (int j = 0; j < 4; ++j) {
        int c = c0 + j;
        float mean = sums[c] * inv_n;
        float var = sums[OUT_CH + c] * inv_n - mean * mean;
        float scale = gamma[c] * rsqrtf(var + 1e-5f);
        float y = (r[j] - mean) * scale + beta[c];
        r[j] = fmaxf(y, 0.0f);
    }
    out[idx] = make_float4(r[0], r[1], r[2], r[3]);
}

// ---------- fallback (atomic scatter) if ws too small ----------

__global__ void __launch_bounds__(256) zero_kernel(float4* __restrict__ out, int n4,
                                                   float* __restrict__ sums) {
    int idx = blockIdx.x * 256 + threadIdx.x;
    if (idx < n4) out[idx] = make_float4(0.f, 0.f, 0.f, 0.f);
    if (blockIdx.x == 0 && threadIdx.x < 2 * OUT_CH) sums[threadIdx.x] = 0.f;
}

__global__ void __launch_bounds__(256) scatter_gemm_kernel(
    const float* __restrict__ feats,
    const float* __restrict__ W,
    const int* __restrict__ in_idx,
    const int* __restrict__ out_idx,
    const int* __restrict__ mask,
    float* __restrict__ acc,
    int R)
{
    const int lane = threadIdx.x & 63;
    const int waveId = threadIdx.x >> 6;
    const int half = waveId & 1;
    const int pair = waveId >> 1;
    const int k = blockIdx.y;
    const int c = half * 64 + lane;

    float wreg[IN_CH];
    const float* __restrict__ wp = W + (size_t)k * IN_CH * OUT_CH + c;
#pragma unroll
    for (int i = 0; i < IN_CH; ++i) wreg[i] = wp[i * OUT_CH];

    const int r0 = blockIdx.x * 128;
    const int rEnd = min(r0 + 128, R);
    const int* __restrict__ maskK = mask + (size_t)k * R;
    const int* __restrict__ inK = in_idx + (size_t)k * R;
    const int* __restrict__ outK = out_idx + (size_t)k * R;

    for (int r = r0 + pair; r < rEnd; r += 2) {
        if (!__builtin_amdgcn_readfirstlane(maskK[r])) continue;
        int in = __builtin_amdgcn_readfirstlane(inK[r]);
        int out = __builtin_amdgcn_readfirstlane(outK[r]);
        const float* __restrict__ f = feats + (size_t)in * IN_CH;
        float s = 0.f, s1 = 0.f;
#pragma unroll
        for (int i = 0; i < IN_CH; i += 2) {
            s = fmaf(wreg[i], f[i], s);
            s1 = fmaf(wreg[i + 1], f[i + 1], s1);
        }
        atomicAdd(acc + (size_t)out * OUT_CH + c, s + s1);
    }
}

__global__ void __launch_bounds__(128) stats_kernel(
    const float* __restrict__ acc,
    float* __restrict__ sums,
    int n_out)
{
    int c = threadIdx.x;
    float s = 0.0f, s2 = 0.0f;
    for (int r = blockIdx.x; r < n_out; r += gridDim.x) {
        float v = acc[(size_t)r * OUT_CH + c];
        s += v;
        s2 += v * v;
    }
    atomicAdd(&sums[c], s);
    atomicAdd(&sums[OUT_CH + c], s2);
}

// ---------- launch ----------

extern "C" void kernel_launch(void* const* d_in, const int* in_sizes, int n_in,
                              void* d_out, int out_size, void* d_ws, size_t ws_size,
                              hipStream_t stream) {
    const float* feats   = (const float*)d_in[0];
    const float* W       = (const float*)d_in[1];
    const float* gamma   = (const float*)d_in[2];
    const float* beta    = (const float*)d_in[3];
    const int*   in_idx  = (const int*)d_in[4];
    const int*   out_idx = (const int*)d_in[5];
    const int*   mask    = (const int*)d_in[6];   // bool stored as int32

    const int R = in_sizes[4] / 9;
    const int nE = 9 * R;
    const int n_out = out_size / OUT_CH;
    const int N_in = in_sizes[0] / IN_CH;
    float* acc = (float*)d_out;

    size_t off_contrib = 0;
    size_t sz_contrib = (size_t)nE * OUT_CH * sizeof(float);
    size_t off_counts = off_contrib + sz_contrib;
    size_t off_list = (off_counts + (size_t)n_out * 4 + 15) & ~(size_t)15;
    size_t off_sums = (off_list + (size_t)n_out * 9 * 4 + 15) & ~(size_t)15;
    size_t off_fb   = (off_sums + 1024 + 15) & ~(size_t)15;
    size_t off_wbt  = (off_fb + (size_t)N_in * IN_CH * 2 + 15) & ~(size_t)15;
    size_t needed = off_wbt + (size_t)9 * OUT_CH * IN_CH * 2;

    if (ws_size >= needed) {
        float*  contrib = (float*)((char*)d_ws + off_contrib);
        int*    counts  = (int*)((char*)d_ws + off_counts);
        int*    list    = (int*)((char*)d_ws + off_list);
        float*  sums    = (float*)((char*)d_ws + off_sums);
        ushort* fb      = (ushort*)((char*)d_ws + off_fb);
        ushort* wbt     = (ushort*)((char*)d_ws + off_wbt);

        zero_meta_kernel<<<(n_out + 255) / 256, 256, 0, stream>>>(counts, n_out, sums);

        int n4 = N_in * IN_CH / 4;
        feats_bf16_kernel<<<(n4 + 255) / 256, 256, 0, stream>>>(
            (const float4*)feats, fb, n4);

        wbt_kernel<<<(9 * OUT_CH * IN_CH + 255) / 256, 256, 0, stream>>>(W, wbt);

        dim3 grid1((R + 63) / 64, 9);
        contrib_mfma_kernel<<<grid1, 256, 0, stream>>>(fb, wbt, in_idx, contrib, R);

        build_kernel<<<(nE + 255) / 256, 256, 0, stream>>>(out_idx, mask, counts, list, nE);

        int blocks2 = (n_out + GS_RPB - 1) / GS_RPB;
        gather_stats_kernel<<<blocks2, 256, 0, stream>>>(
            (const float2*)contrib, counts, list, (float2*)acc, sums, n_out);

        int total4 = out_size / 4;
        bn_relu_kernel<<<(total4 + 255) / 256, 256, 0, stream>>>(
            (float4*)acc, sums, gamma, beta, total4, 1.0f / (float)n_out);
    } else {
        float* sums = (float*)d_ws;
        int n4 = out_size / 4;
        zero_kernel<<<(n4 + 255) / 256, 256, 0, stream>>>((float4*)acc, n4, sums);

        dim3 grid((R + 127) / 128, 9);
        scatter_gemm_kernel<<<grid, 256, 0, stream>>>(feats, W, in_idx, out_idx, mask, acc, R);

        stats_kernel<<<2048, 128, 0, stream>>>(acc, sums, n_out);

        int total4 = out_size / 4;
        bn_relu_kernel<<<(total4 + 255) / 256, 256, 0, stream>>>(
            (float4*)acc, sums, gamma, beta, total4, 1.0f / (float)n_out);
    }
}